// Round 2
// baseline (755.458 us; speedup 1.0000x reference)
//
#include <hip/hip_runtime.h>
#include <hip/hip_bf16.h>

#define NN   50000
#define EE   1600000
#define FIN  128
#define FOUT 64
#define BETA  0.5f
#define ALPHA 0.2f

// Read element i of a buffer that is either fp32 (isf32=1) or bf16 (isf32=0).
__device__ __forceinline__ float load_any(const void* p, long i, int isf32) {
    if (isf32) return ((const float*)p)[i];
    unsigned int b = ((unsigned int)(((const unsigned short*)p)[i])) << 16;
    return __uint_as_float(b);
}

// ---------------------------------------------------------------------------
// Kernel 0: per-tensor dtype detection. A bf16 tensor read as bf16 has small
// values; an fp32 tensor read as bf16 hits its low-16-bit words -> random
// exponent fields -> huge/NaN values. Reading n bf16 (=2n bytes) is in-bounds
// under both hypotheses (fp32 buffer is 4n bytes). flags[t]=1 means fp32.
// ---------------------------------------------------------------------------
__global__ __launch_bounds__(256) void detect_kernel(
    const void* inp, const void* Mv, const void* W, const void* a, int* flags)
{
    const void* ptrs[4] = { inp, Mv, W, a };
    const long  cnts[4] = { (long)NN * FIN, (long)EE, (long)FIN * FOUT, 2L * FOUT };
    const int t = blockIdx.x;
    const unsigned short* p = (const unsigned short*)ptrs[t];
    const long n = cnts[t];
    const long stride = (n > 65536) ? (n / 65536) : 1;

    float m = 0.f;
    for (long i = (long)threadIdx.x * stride; i < n; i += 256 * stride) {
        unsigned int b = ((unsigned int)p[i]) << 16;
        float v = __uint_as_float(b);
        if (isnan(v) || isinf(v)) { m = 1e30f; break; }
        m = fmaxf(m, fabsf(v));
    }
    __shared__ float sm[256];
    sm[threadIdx.x] = m;
    __syncthreads();
    for (int s = 128; s > 0; s >>= 1) {
        if (threadIdx.x < (unsigned)s) sm[threadIdx.x] = fmaxf(sm[threadIdx.x], sm[threadIdx.x + s]);
        __syncthreads();
    }
    if (threadIdx.x == 0) flags[t] = (sm[0] > 1e4f) ? 1 : 0;
}

// ---------------------------------------------------------------------------
// Kernel 1: h = X @ W (fp32 accum), fused s1 = h.a[:64], s2 = h.a[64:]
// One wave per node row; lane = output column.
// ---------------------------------------------------------------------------
__global__ __launch_bounds__(256) void gemm_proj_kernel(
    const void* __restrict__ inp,   // [NN, FIN]
    const void* __restrict__ W,     // [FIN, FOUT]
    const void* __restrict__ a,     // [2*FOUT]
    const int* __restrict__ flags,
    float* __restrict__ h,          // [NN, FOUT]
    float* __restrict__ s1,         // [NN]
    float* __restrict__ s2)         // [NN]
{
    __shared__ float Ws[FIN * FOUT];          // 32 KB
    __shared__ float rows[4][FIN];            // 2 KB

    const int tid  = threadIdx.x;
    const int wave = tid >> 6;
    const int lane = tid & 63;
    const int row  = blockIdx.x * 4 + wave;

    const int fI = flags[0], fW = flags[2], fA = flags[3];

    for (int i = tid; i < FIN * FOUT; i += 256)
        Ws[i] = load_any(W, i, fW);

    if (row < NN) {
        rows[wave][lane]      = load_any(inp, (long)row * FIN + lane, fI);
        rows[wave][lane + 64] = load_any(inp, (long)row * FIN + lane + 64, fI);
    }
    __syncthreads();
    if (row >= NN) return;

    float acc = 0.f;
    #pragma unroll
    for (int k = 0; k < FIN; ++k)
        acc = fmaf(rows[wave][k], Ws[k * FOUT + lane], acc);

    h[row * FOUT + lane] = acc;

    float v1 = acc * load_any(a, lane, fA);
    float v2 = acc * load_any(a, lane + 64, fA);
    #pragma unroll
    for (int off = 32; off > 0; off >>= 1) {
        v1 += __shfl_down(v1, off, 64);
        v2 += __shfl_down(v2, off, 64);
    }
    if (lane == 0) { s1[row] = v1; s2[row] = v2; }
}

// ---------------------------------------------------------------------------
// Kernel 2: per-edge attention weight + scatter-add aggregation.
// One wave per edge; lane = feature.
// ---------------------------------------------------------------------------
__global__ __launch_bounds__(256) void edge_kernel(
    const int* __restrict__ edge,   // [2, EE]
    const void* __restrict__ Mv,    // [EE]
    const int* __restrict__ flags,
    const float* __restrict__ h,
    const float* __restrict__ s1,
    const float* __restrict__ s2,
    float* __restrict__ rowsum,
    float* __restrict__ hp)
{
    const int wave = threadIdx.x >> 6;
    const int lane = threadIdx.x & 63;
    const int e = blockIdx.x * 4 + wave;
    if (e >= EE) return;

    const int fM = flags[1];
    const int src = edge[e];
    const int dst = edge[EE + e];

    const float bias = load_any(Mv, e, fM) * BETA + (1.f - BETA);
    const float x  = s1[src] + bias * s2[dst];
    const float lr = x > 0.f ? x : ALPHA * x;
    const float ee = __expf(lr);

    if (lane == 0) atomicAdd(&rowsum[src], ee);

    const float hv = h[(long)dst * FOUT + lane];
    atomicAdd(&hp[(long)src * FOUT + lane], ee * hv);
}

// ---------------------------------------------------------------------------
// Kernel 3: out = elu(h_prime / rowsum); dtype of out follows input's flag.
// ---------------------------------------------------------------------------
__global__ __launch_bounds__(256) void finalize_kernel(
    const float* __restrict__ hp,
    const float* __restrict__ rowsum,
    const int* __restrict__ flags,
    void* __restrict__ out)
{
    const int i = blockIdx.x * 256 + threadIdx.x;
    if (i >= NN * FOUT) return;
    const float v = hp[i] / rowsum[i >> 6];
    const float r = v > 0.f ? v : (__expf(v) - 1.f);
    if (flags[0]) {
        ((float*)out)[i] = r;
    } else {
        // round-to-nearest-even fp32 -> bf16
        unsigned int b = __float_as_uint(r);
        unsigned int rounded = (b + 0x7FFF + ((b >> 16) & 1)) >> 16;
        ((unsigned short*)out)[i] = (unsigned short)rounded;
    }
}

extern "C" void kernel_launch(void* const* d_in, const int* in_sizes, int n_in,
                              void* d_out, int out_size, void* d_ws, size_t ws_size,
                              hipStream_t stream) {
    const void* inp  = d_in[0];
    const void* Mv   = d_in[1];
    const void* W    = d_in[2];
    const void* a    = d_in[3];
    const int*  edge = (const int*)d_in[4];

    // ws layout: flags (64 B pad) | h[NN*64] | s1[NN] | s2[NN] | rowsum[NN] | hp[NN*64]
    int*   flags  = (int*)d_ws;
    float* base   = (float*)((char*)d_ws + 64);
    float* h      = base;
    float* s1     = h  + (size_t)NN * FOUT;
    float* s2     = s1 + NN;
    float* rowsum = s2 + NN;
    float* hp     = rowsum + NN;

    detect_kernel<<<4, 256, 0, stream>>>(inp, Mv, W, a, flags);
    hipMemsetAsync(rowsum, 0, (size_t)(NN + (size_t)NN * FOUT) * sizeof(float), stream);
    gemm_proj_kernel<<<(NN + 3) / 4, 256, 0, stream>>>(inp, W, a, flags, h, s1, s2);
    edge_kernel<<<(EE + 3) / 4, 256, 0, stream>>>(edge, Mv, flags, h, s1, s2, rowsum, hp);
    finalize_kernel<<<(NN * FOUT + 255) / 256, 256, 0, stream>>>(hp, rowsum, flags, d_out);
}

// Round 3
// 490.006 us; speedup vs baseline: 1.5417x; 1.5417x over previous
//
#include <hip/hip_runtime.h>
#include <hip/hip_bf16.h>

#define NN   50000
#define EE   1600000
#define FIN  128
#define FOUT 64
#define BETA  0.5f
#define ALPHA 0.2f
#define NCHUNK 196          // ceil(NN/256)

// Read element i of a buffer that is either fp32 (isf32=1) or bf16 (isf32=0).
__device__ __forceinline__ float load_any(const void* p, long i, int isf32) {
    if (isf32) return ((const float*)p)[i];
    unsigned int b = ((unsigned int)(((const unsigned short*)p)[i])) << 16;
    return __uint_as_float(b);
}

__device__ __forceinline__ unsigned short f32_to_bf16_rne(float f) {
    unsigned int b = __float_as_uint(f);
    return (unsigned short)((b + 0x7FFF + ((b >> 16) & 1)) >> 16);
}

__device__ __forceinline__ float bf16_to_f32(unsigned short u) {
    return __uint_as_float(((unsigned int)u) << 16);
}

// ---------------------------------------------------------------------------
// Kernel 0: per-tensor dtype detection (fp32 misread as bf16 -> huge values).
// flags[t]=1 means fp32.
// ---------------------------------------------------------------------------
__global__ __launch_bounds__(256) void detect_kernel(
    const void* inp, const void* Mv, const void* W, const void* a, int* flags)
{
    const void* ptrs[4] = { inp, Mv, W, a };
    const long  cnts[4] = { (long)NN * FIN, (long)EE, (long)FIN * FOUT, 2L * FOUT };
    const int t = blockIdx.x;
    const unsigned short* p = (const unsigned short*)ptrs[t];
    const long n = cnts[t];
    const long stride = (n > 65536) ? (n / 65536) : 1;

    float m = 0.f;
    for (long i = (long)threadIdx.x * stride; i < n; i += 256 * stride) {
        unsigned int b = ((unsigned int)p[i]) << 16;
        float v = __uint_as_float(b);
        if (isnan(v) || isinf(v)) { m = 1e30f; break; }
        m = fmaxf(m, fabsf(v));
    }
    __shared__ float sm[256];
    sm[threadIdx.x] = m;
    __syncthreads();
    for (int s = 128; s > 0; s >>= 1) {
        if (threadIdx.x < (unsigned)s) sm[threadIdx.x] = fmaxf(sm[threadIdx.x], sm[threadIdx.x + s]);
        __syncthreads();
    }
    if (threadIdx.x == 0) flags[t] = (sm[0] > 1e4f) ? 1 : 0;
}

// ---------------------------------------------------------------------------
// Kernel 1: h = X @ W (fp32 accum, stored bf16), fused s1/s2 projections.
// 16 rows/block, 4 rows/wave (amortizes the 32 KB W staging 4x vs R2).
// 3125 blocks * 16 = 50000 exactly (no bounds checks on rows).
// ---------------------------------------------------------------------------
__global__ __launch_bounds__(256) void gemm_proj_kernel(
    const void* __restrict__ inp,   // [NN, FIN]
    const void* __restrict__ W,     // [FIN, FOUT]
    const void* __restrict__ a,     // [2*FOUT]
    const int* __restrict__ flags,
    unsigned short* __restrict__ h, // [NN, FOUT] bf16
    float* __restrict__ s1,         // [NN]
    float* __restrict__ s2)         // [NN]
{
    __shared__ float Ws[FIN * FOUT];   // 32 KB
    __shared__ float rows[16][FIN];    // 8 KB

    const int tid  = threadIdx.x;
    const int wave = tid >> 6;
    const int lane = tid & 63;
    const int rbase = blockIdx.x * 16;

    const int fI = flags[0], fW = flags[2], fA = flags[3];

    for (int i = tid; i < FIN * FOUT; i += 256)
        Ws[i] = load_any(W, i, fW);

    for (int i = tid; i < 16 * FIN; i += 256) {
        const int r = i >> 7, c = i & 127;
        rows[r][c] = load_any(inp, (long)(rbase + r) * FIN + c, fI);
    }
    __syncthreads();

    const int r0 = wave * 4;
    float a0 = 0.f, a1 = 0.f, a2 = 0.f, a3 = 0.f;
    #pragma unroll 8
    for (int k = 0; k < FIN; ++k) {
        const float w = Ws[k * FOUT + lane];
        a0 = fmaf(rows[r0 + 0][k], w, a0);
        a1 = fmaf(rows[r0 + 1][k], w, a1);
        a2 = fmaf(rows[r0 + 2][k], w, a2);
        a3 = fmaf(rows[r0 + 3][k], w, a3);
    }

    const int row = rbase + r0;
    h[(long)(row + 0) * FOUT + lane] = f32_to_bf16_rne(a0);
    h[(long)(row + 1) * FOUT + lane] = f32_to_bf16_rne(a1);
    h[(long)(row + 2) * FOUT + lane] = f32_to_bf16_rne(a2);
    h[(long)(row + 3) * FOUT + lane] = f32_to_bf16_rne(a3);

    const float av1 = load_any(a, lane, fA);
    const float av2 = load_any(a, lane + 64, fA);
    float accs[4] = { a0, a1, a2, a3 };
    #pragma unroll
    for (int r = 0; r < 4; ++r) {
        float v1 = accs[r] * av1;
        float v2 = accs[r] * av2;
        #pragma unroll
        for (int off = 32; off > 0; off >>= 1) {
            v1 += __shfl_down(v1, off, 64);
            v2 += __shfl_down(v2, off, 64);
        }
        if (lane == 0) { s1[row + r] = v1; s2[row + r] = v2; }
    }
}

// ---------------------------------------------------------------------------
// CSR build: histogram -> scan (3 kernels) -> scatter of (dst, edge_e) pairs.
// ---------------------------------------------------------------------------
__global__ __launch_bounds__(256) void hist_kernel(
    const int* __restrict__ edge, int* __restrict__ counts)
{
    const int e = blockIdx.x * 256 + threadIdx.x;
    if (e < EE) atomicAdd(&counts[edge[e]], 1);
}

// block-wide exclusive scan helper state: returns exclusive prefix; total via last thread
__global__ __launch_bounds__(256) void scan1_kernel(
    const int* __restrict__ counts, int* __restrict__ rowptr, int* __restrict__ bsums)
{
    const int tid = threadIdx.x, wave = tid >> 6, lane = tid & 63;
    const int i = blockIdx.x * 256 + tid;
    const int c = (i < NN) ? counts[i] : 0;
    int x = c;
    #pragma unroll
    for (int off = 1; off < 64; off <<= 1) {
        int y = __shfl_up(x, off, 64);
        if (lane >= off) x += y;
    }
    __shared__ int wsum[4];
    if (lane == 63) wsum[wave] = x;
    __syncthreads();
    int wb = 0;
    for (int w = 0; w < wave; ++w) wb += wsum[w];
    if (i < NN) rowptr[i] = wb + x - c;           // exclusive within chunk
    if (tid == 255) bsums[blockIdx.x] = wb + x;   // chunk total
}

__global__ __launch_bounds__(256) void scan2_kernel(
    int* __restrict__ bsums, int* __restrict__ boffs)
{
    const int tid = threadIdx.x, wave = tid >> 6, lane = tid & 63;
    const int c = (tid < NCHUNK) ? bsums[tid] : 0;
    int x = c;
    #pragma unroll
    for (int off = 1; off < 64; off <<= 1) {
        int y = __shfl_up(x, off, 64);
        if (lane >= off) x += y;
    }
    __shared__ int wsum[4];
    if (lane == 63) wsum[wave] = x;
    __syncthreads();
    int wb = 0;
    for (int w = 0; w < wave; ++w) wb += wsum[w];
    if (tid < NCHUNK) boffs[tid] = wb + x - c;
}

__global__ __launch_bounds__(256) void scan3_kernel(
    int* __restrict__ rowptr, const int* __restrict__ boffs, int* __restrict__ cursor)
{
    const int i = blockIdx.x * 256 + threadIdx.x;
    if (i < NN) {
        const int v = rowptr[i] + boffs[blockIdx.x];
        rowptr[i] = v;
        cursor[i] = v;
    }
    if (i == 0) rowptr[NN] = EE;
}

__global__ __launch_bounds__(256) void scatter_kernel(
    const int* __restrict__ edge,
    const void* __restrict__ Mv,
    const int* __restrict__ flags,
    const float* __restrict__ s1,
    const float* __restrict__ s2,
    int* __restrict__ cursor,
    int2* __restrict__ pairs)
{
    const int e = blockIdx.x * 256 + threadIdx.x;
    if (e >= EE) return;
    const int src = edge[e];
    const int dst = edge[EE + e];
    const float bias = load_any(Mv, e, flags[1]) * BETA + (1.f - BETA);
    const float x  = s1[src] + bias * s2[dst];
    const float lr = x > 0.f ? x : ALPHA * x;
    const float ee = __expf(lr);
    const int pos = atomicAdd(&cursor[src], 1);
    pairs[pos] = make_int2(dst, __float_as_int(ee));
}

// ---------------------------------------------------------------------------
// CSR-vector SpMM with fused finalize: one wave per src row; register
// accumulation; single write. out = elu(acc/rowsum).
// 12500 blocks * 4 rows = 50000 exactly.
// ---------------------------------------------------------------------------
__global__ __launch_bounds__(256) void spmm_kernel(
    const int* __restrict__ rowptr,
    const int2* __restrict__ pairs,
    const unsigned short* __restrict__ h,   // bf16 [NN, FOUT]
    const int* __restrict__ flags,
    void* __restrict__ out)
{
    const int wave = threadIdx.x >> 6;
    const int lane = threadIdx.x & 63;
    const int row  = blockIdx.x * 4 + wave;

    const int beg = rowptr[row];
    const int end = rowptr[row + 1];

    float acc = 0.f, rsum = 0.f;
    int j = beg;
    for (; j + 3 < end; j += 4) {
        const int2 p0 = pairs[j + 0];
        const int2 p1 = pairs[j + 1];
        const int2 p2 = pairs[j + 2];
        const int2 p3 = pairs[j + 3];
        const float h0 = bf16_to_f32(h[(long)p0.x * FOUT + lane]);
        const float h1 = bf16_to_f32(h[(long)p1.x * FOUT + lane]);
        const float h2 = bf16_to_f32(h[(long)p2.x * FOUT + lane]);
        const float h3 = bf16_to_f32(h[(long)p3.x * FOUT + lane]);
        const float v0 = __int_as_float(p0.y);
        const float v1 = __int_as_float(p1.y);
        const float v2 = __int_as_float(p2.y);
        const float v3 = __int_as_float(p3.y);
        rsum += (v0 + v1) + (v2 + v3);
        acc = fmaf(v0, h0, acc);
        acc = fmaf(v1, h1, acc);
        acc = fmaf(v2, h2, acc);
        acc = fmaf(v3, h3, acc);
    }
    for (; j < end; ++j) {
        const int2 p = pairs[j];
        const float hv = bf16_to_f32(h[(long)p.x * FOUT + lane]);
        const float v  = __int_as_float(p.y);
        rsum += v;
        acc = fmaf(v, hv, acc);
    }

    const float q = acc / rsum;
    const float r = q > 0.f ? q : (__expf(q) - 1.f);
    if (flags[0]) ((float*)out)[(long)row * FOUT + lane] = r;
    else ((unsigned short*)out)[(long)row * FOUT + lane] = f32_to_bf16_rne(r);
}

extern "C" void kernel_launch(void* const* d_in, const int* in_sizes, int n_in,
                              void* d_out, int out_size, void* d_ws, size_t ws_size,
                              hipStream_t stream) {
    const void* inp  = d_in[0];
    const void* Mv   = d_in[1];
    const void* W    = d_in[2];
    const void* a    = d_in[3];
    const int*  edge = (const int*)d_in[4];

    // ws layout (256B-aligned segments):
    // flags[4] | h bf16[NN*64] | s1[NN] | s2[NN] | rowptr[NN+1] | cursor[NN] |
    // bsums[NCHUNK] | boffs[NCHUNK] | pairs int2[EE]
    char* p = (char*)d_ws;
    int*            flags  = (int*)p;                          p += 256;
    unsigned short* h      = (unsigned short*)p;               p += ((size_t)NN * FOUT * 2 + 255) / 256 * 256;
    float*          s1     = (float*)p;                        p += ((size_t)NN * 4 + 255) / 256 * 256;
    float*          s2     = (float*)p;                        p += ((size_t)NN * 4 + 255) / 256 * 256;
    int*            rowptr = (int*)p;                          p += ((size_t)(NN + 1) * 4 + 255) / 256 * 256;
    int*            cursor = (int*)p;                          p += ((size_t)NN * 4 + 255) / 256 * 256;
    int*            bsums  = (int*)p;                          p += (NCHUNK * 4 + 255) / 256 * 256;
    int*            boffs  = (int*)p;                          p += (NCHUNK * 4 + 255) / 256 * 256;
    int2*           pairs  = (int2*)p;

    detect_kernel<<<4, 256, 0, stream>>>(inp, Mv, W, a, flags);
    hipMemsetAsync(cursor, 0, (size_t)NN * sizeof(int), stream);   // cursor doubles as counts
    gemm_proj_kernel<<<NN / 16, 256, 0, stream>>>(inp, W, a, flags, h, s1, s2);
    hist_kernel<<<(EE + 255) / 256, 256, 0, stream>>>(edge, cursor);
    scan1_kernel<<<NCHUNK, 256, 0, stream>>>(cursor, rowptr, bsums);
    scan2_kernel<<<1, 256, 0, stream>>>(bsums, boffs);
    scan3_kernel<<<NCHUNK, 256, 0, stream>>>(rowptr, boffs, cursor);
    scatter_kernel<<<(EE + 255) / 256, 256, 0, stream>>>(edge, Mv, flags, s1, s2, cursor, pairs);
    spmm_kernel<<<NN / 4, 256, 0, stream>>>(rowptr, pairs, h, flags, d_out);
}

// Round 4
// 335.058 us; speedup vs baseline: 2.2547x; 1.4625x over previous
//
#include <hip/hip_runtime.h>
#include <hip/hip_bf16.h>

#define NN   50000
#define EE   1600000
#define FIN  128
#define FOUT 64
#define BETA  0.5f
#define ALPHA 0.2f
#define NCHUNK 196          // ceil(NN/256)

// Read element i of a buffer that is either fp32 (isf32=1) or bf16 (isf32=0).
__device__ __forceinline__ float load_any(const void* p, long i, int isf32) {
    if (isf32) return ((const float*)p)[i];
    unsigned int b = ((unsigned int)(((const unsigned short*)p)[i])) << 16;
    return __uint_as_float(b);
}

__device__ __forceinline__ unsigned short f32_to_bf16_rne(float f) {
    unsigned int b = __float_as_uint(f);
    return (unsigned short)((b + 0x7FFF + ((b >> 16) & 1)) >> 16);
}

__device__ __forceinline__ float bf16_to_f32(unsigned short u) {
    return __uint_as_float(((unsigned int)u) << 16);
}

// ---------------------------------------------------------------------------
// Kernel 0: per-tensor dtype detection, sampled. An fp32 tensor misread as
// bf16 hits low-16-bit mantissa words at even indices -> |value| > 1e4 with
// ~45% probability per sample; 256 samples -> P(miss) ~ 1e-67. One block per
// tensor, ONE strided load per thread (no serial latency chain).
// flags[t]=1 means fp32.
// ---------------------------------------------------------------------------
__global__ __launch_bounds__(256) void detect_kernel(
    const void* inp, const void* Mv, const void* W, const void* a, int* flags)
{
    const void* ptrs[4] = { inp, Mv, W, a };
    const long  cnts[4] = { (long)NN * FIN, (long)EE, (long)FIN * FOUT, 2L * FOUT };
    const int t = blockIdx.x;
    const unsigned short* p = (const unsigned short*)ptrs[t];
    const long half = cnts[t] >> 1;              // # of even positions
    long step = half / 256; if (step == 0) step = 1;
    const long pos = 2 * (((long)threadIdx.x * step) % half);   // even index

    const float v = bf16_to_f32(p[pos]);
    const int bad = (isnan(v) || fabsf(v) > 1e4f) ? 1 : 0;

    __shared__ int sbad[256];
    sbad[threadIdx.x] = bad;
    __syncthreads();
    for (int s = 128; s > 0; s >>= 1) {
        if (threadIdx.x < (unsigned)s) sbad[threadIdx.x] |= sbad[threadIdx.x + s];
        __syncthreads();
    }
    if (threadIdx.x == 0) flags[t] = sbad[0];
}

// ---------------------------------------------------------------------------
// Kernel 1: h = X @ W (fp32 accum, stored bf16), fused s1/s2 projections.
// 16 rows/block, 4 rows/wave. 3125 blocks * 16 = 50000 exactly.
// ---------------------------------------------------------------------------
__global__ __launch_bounds__(256) void gemm_proj_kernel(
    const void* __restrict__ inp,   // [NN, FIN]
    const void* __restrict__ W,     // [FIN, FOUT]
    const void* __restrict__ a,     // [2*FOUT]
    const int* __restrict__ flags,
    unsigned short* __restrict__ h, // [NN, FOUT] bf16
    float* __restrict__ s1,         // [NN]
    float* __restrict__ s2)         // [NN]
{
    __shared__ float Ws[FIN * FOUT];   // 32 KB
    __shared__ float rows[16][FIN];    // 8 KB

    const int tid  = threadIdx.x;
    const int wave = tid >> 6;
    const int lane = tid & 63;
    const int rbase = blockIdx.x * 16;

    const int fI = flags[0], fW = flags[2], fA = flags[3];

    for (int i = tid; i < FIN * FOUT; i += 256)
        Ws[i] = load_any(W, i, fW);

    for (int i = tid; i < 16 * FIN; i += 256) {
        const int r = i >> 7, c = i & 127;
        rows[r][c] = load_any(inp, (long)(rbase + r) * FIN + c, fI);
    }
    __syncthreads();

    const int r0 = wave * 4;
    float a0 = 0.f, a1 = 0.f, a2 = 0.f, a3 = 0.f;
    #pragma unroll 8
    for (int k = 0; k < FIN; ++k) {
        const float w = Ws[k * FOUT + lane];
        a0 = fmaf(rows[r0 + 0][k], w, a0);
        a1 = fmaf(rows[r0 + 1][k], w, a1);
        a2 = fmaf(rows[r0 + 2][k], w, a2);
        a3 = fmaf(rows[r0 + 3][k], w, a3);
    }

    const int row = rbase + r0;
    h[(long)(row + 0) * FOUT + lane] = f32_to_bf16_rne(a0);
    h[(long)(row + 1) * FOUT + lane] = f32_to_bf16_rne(a1);
    h[(long)(row + 2) * FOUT + lane] = f32_to_bf16_rne(a2);
    h[(long)(row + 3) * FOUT + lane] = f32_to_bf16_rne(a3);

    const float av1 = load_any(a, lane, fA);
    const float av2 = load_any(a, lane + 64, fA);
    float accs[4] = { a0, a1, a2, a3 };
    #pragma unroll
    for (int r = 0; r < 4; ++r) {
        float v1 = accs[r] * av1;
        float v2 = accs[r] * av2;
        #pragma unroll
        for (int off = 32; off > 0; off >>= 1) {
            v1 += __shfl_down(v1, off, 64);
            v2 += __shfl_down(v2, off, 64);
        }
        if (lane == 0) { s1[row + r] = v1; s2[row + r] = v2; }
    }
}

// ---------------------------------------------------------------------------
// CSR build: histogram -> scan (3 kernels) -> scatter of (dst, edge_e) pairs.
// ---------------------------------------------------------------------------
__global__ __launch_bounds__(256) void hist_kernel(
    const int* __restrict__ edge, int* __restrict__ counts)
{
    const int e = blockIdx.x * 256 + threadIdx.x;
    if (e < EE) atomicAdd(&counts[edge[e]], 1);
}

__global__ __launch_bounds__(256) void scan1_kernel(
    const int* __restrict__ counts, int* __restrict__ rowptr, int* __restrict__ bsums)
{
    const int tid = threadIdx.x, wave = tid >> 6, lane = tid & 63;
    const int i = blockIdx.x * 256 + tid;
    const int c = (i < NN) ? counts[i] : 0;
    int x = c;
    #pragma unroll
    for (int off = 1; off < 64; off <<= 1) {
        int y = __shfl_up(x, off, 64);
        if (lane >= off) x += y;
    }
    __shared__ int wsum[4];
    if (lane == 63) wsum[wave] = x;
    __syncthreads();
    int wb = 0;
    for (int w = 0; w < wave; ++w) wb += wsum[w];
    if (i < NN) rowptr[i] = wb + x - c;
    if (tid == 255) bsums[blockIdx.x] = wb + x;
}

__global__ __launch_bounds__(256) void scan2_kernel(
    int* __restrict__ bsums, int* __restrict__ boffs)
{
    const int tid = threadIdx.x, wave = tid >> 6, lane = tid & 63;
    const int c = (tid < NCHUNK) ? bsums[tid] : 0;
    int x = c;
    #pragma unroll
    for (int off = 1; off < 64; off <<= 1) {
        int y = __shfl_up(x, off, 64);
        if (lane >= off) x += y;
    }
    __shared__ int wsum[4];
    if (lane == 63) wsum[wave] = x;
    __syncthreads();
    int wb = 0;
    for (int w = 0; w < wave; ++w) wb += wsum[w];
    if (tid < NCHUNK) boffs[tid] = wb + x - c;
}

__global__ __launch_bounds__(256) void scan3_kernel(
    int* __restrict__ rowptr, const int* __restrict__ boffs, int* __restrict__ cursor)
{
    const int i = blockIdx.x * 256 + threadIdx.x;
    if (i < NN) {
        const int v = rowptr[i] + boffs[blockIdx.x];
        rowptr[i] = v;
        cursor[i] = v;
    }
    if (i == 0) rowptr[NN] = EE;
}

__global__ __launch_bounds__(256) void scatter_kernel(
    const int* __restrict__ edge,
    const void* __restrict__ Mv,
    const int* __restrict__ flags,
    const float* __restrict__ s1,
    const float* __restrict__ s2,
    int* __restrict__ cursor,
    int2* __restrict__ pairs)
{
    const int e = blockIdx.x * 256 + threadIdx.x;
    if (e >= EE) return;
    const int src = edge[e];
    const int dst = edge[EE + e];
    const float bias = load_any(Mv, e, flags[1]) * BETA + (1.f - BETA);
    const float x  = s1[src] + bias * s2[dst];
    const float lr = x > 0.f ? x : ALPHA * x;
    const float ee = __expf(lr);
    const int pos = atomicAdd(&cursor[src], 1);
    pairs[pos] = make_int2(dst, __float_as_int(ee));
}

// ---------------------------------------------------------------------------
// CSR-vector SpMM, fused finalize. One wave per src row; 32 lanes per edge
// (ushort2 = 2 features/lane), 2 edges in flight per wave, unrolled x4.
// Halves combined with one shfl_xor(32). 12500 blocks * 4 rows = 50000.
// ---------------------------------------------------------------------------
__global__ __launch_bounds__(256) void spmm_kernel(
    const int* __restrict__ rowptr,
    const int2* __restrict__ pairs,
    const unsigned short* __restrict__ h,   // bf16 [NN, FOUT]
    const int* __restrict__ flags,
    void* __restrict__ out)
{
    const int wave = threadIdx.x >> 6;
    const int lane = threadIdx.x & 63;
    const int half = lane >> 5;          // which of 2 in-flight edges
    const int sl   = lane & 31;          // sub-lane: features 2*sl, 2*sl+1
    const int row  = blockIdx.x * 4 + wave;

    const int beg = rowptr[row];
    const int end = rowptr[row + 1];

    float acc0 = 0.f, acc1 = 0.f, rsum = 0.f;
    int j = beg;
    for (; j + 7 < end; j += 8) {
        const int2 p0 = pairs[j + 0 + half];
        const int2 p1 = pairs[j + 2 + half];
        const int2 p2 = pairs[j + 4 + half];
        const int2 p3 = pairs[j + 6 + half];
        const ushort2 h0 = *(const ushort2*)&h[(long)p0.x * FOUT + 2 * sl];
        const ushort2 h1 = *(const ushort2*)&h[(long)p1.x * FOUT + 2 * sl];
        const ushort2 h2 = *(const ushort2*)&h[(long)p2.x * FOUT + 2 * sl];
        const ushort2 h3 = *(const ushort2*)&h[(long)p3.x * FOUT + 2 * sl];
        const float v0 = __int_as_float(p0.y);
        const float v1 = __int_as_float(p1.y);
        const float v2 = __int_as_float(p2.y);
        const float v3 = __int_as_float(p3.y);
        rsum += (v0 + v1) + (v2 + v3);
        acc0 = fmaf(v0, bf16_to_f32(h0.x), acc0);
        acc1 = fmaf(v0, bf16_to_f32(h0.y), acc1);
        acc0 = fmaf(v1, bf16_to_f32(h1.x), acc0);
        acc1 = fmaf(v1, bf16_to_f32(h1.y), acc1);
        acc0 = fmaf(v2, bf16_to_f32(h2.x), acc0);
        acc1 = fmaf(v2, bf16_to_f32(h2.y), acc1);
        acc0 = fmaf(v3, bf16_to_f32(h3.x), acc0);
        acc1 = fmaf(v3, bf16_to_f32(h3.y), acc1);
    }
    for (; j + 1 < end; j += 2) {
        const int2 p = pairs[j + half];
        const ushort2 hv = *(const ushort2*)&h[(long)p.x * FOUT + 2 * sl];
        const float v = __int_as_float(p.y);
        rsum += v;
        acc0 = fmaf(v, bf16_to_f32(hv.x), acc0);
        acc1 = fmaf(v, bf16_to_f32(hv.y), acc1);
    }
    if (j < end && half == 0) {
        const int2 p = pairs[j];
        const ushort2 hv = *(const ushort2*)&h[(long)p.x * FOUT + 2 * sl];
        const float v = __int_as_float(p.y);
        rsum += v;
        acc0 = fmaf(v, bf16_to_f32(hv.x), acc0);
        acc1 = fmaf(v, bf16_to_f32(hv.y), acc1);
    }

    // combine the two halves
    acc0 += __shfl_xor(acc0, 32, 64);
    acc1 += __shfl_xor(acc1, 32, 64);
    rsum += __shfl_xor(rsum, 32, 64);

    if (half == 0) {
        const float inv = 1.f / rsum;
        float q0 = acc0 * inv;
        float q1 = acc1 * inv;
        q0 = q0 > 0.f ? q0 : (__expf(q0) - 1.f);
        q1 = q1 > 0.f ? q1 : (__expf(q1) - 1.f);
        if (flags[0]) {
            float2* o = (float2*)((float*)out + (long)row * FOUT + 2 * sl);
            *o = make_float2(q0, q1);
        } else {
            ushort2* o = (ushort2*)((unsigned short*)out + (long)row * FOUT + 2 * sl);
            *o = make_ushort2(f32_to_bf16_rne(q0), f32_to_bf16_rne(q1));
        }
    }
}

extern "C" void kernel_launch(void* const* d_in, const int* in_sizes, int n_in,
                              void* d_out, int out_size, void* d_ws, size_t ws_size,
                              hipStream_t stream) {
    const void* inp  = d_in[0];
    const void* Mv   = d_in[1];
    const void* W    = d_in[2];
    const void* a    = d_in[3];
    const int*  edge = (const int*)d_in[4];

    char* p = (char*)d_ws;
    int*            flags  = (int*)p;                          p += 256;
    unsigned short* h      = (unsigned short*)p;               p += ((size_t)NN * FOUT * 2 + 255) / 256 * 256;
    float*          s1     = (float*)p;                        p += ((size_t)NN * 4 + 255) / 256 * 256;
    float*          s2     = (float*)p;                        p += ((size_t)NN * 4 + 255) / 256 * 256;
    int*            rowptr = (int*)p;                          p += ((size_t)(NN + 1) * 4 + 255) / 256 * 256;
    int*            cursor = (int*)p;                          p += ((size_t)NN * 4 + 255) / 256 * 256;
    int*            bsums  = (int*)p;                          p += (NCHUNK * 4 + 255) / 256 * 256;
    int*            boffs  = (int*)p;                          p += (NCHUNK * 4 + 255) / 256 * 256;
    int2*           pairs  = (int2*)p;

    detect_kernel<<<4, 256, 0, stream>>>(inp, Mv, W, a, flags);
    hipMemsetAsync(cursor, 0, (size_t)NN * sizeof(int), stream);   // cursor doubles as counts
    gemm_proj_kernel<<<NN / 16, 256, 0, stream>>>(inp, W, a, flags, h, s1, s2);
    hist_kernel<<<(EE + 255) / 256, 256, 0, stream>>>(edge, cursor);
    scan1_kernel<<<NCHUNK, 256, 0, stream>>>(cursor, rowptr, bsums);
    scan2_kernel<<<1, 256, 0, stream>>>(bsums, boffs);
    scan3_kernel<<<NCHUNK, 256, 0, stream>>>(rowptr, boffs, cursor);
    scatter_kernel<<<(EE + 255) / 256, 256, 0, stream>>>(edge, Mv, flags, s1, s2, cursor, pairs);
    spmm_kernel<<<NN / 4, 256, 0, stream>>>(rowptr, pairs, h, flags, d_out);
}

// Round 5
// 329.054 us; speedup vs baseline: 2.2959x; 1.0182x over previous
//
#include <hip/hip_runtime.h>
#include <hip/hip_bf16.h>

#define NN   50000
#define EE   1600000
#define FIN  128
#define FOUT 64
#define BETA  0.5f
#define ALPHA 0.2f
#define NCHUNK 196          // ceil(NN/256)
#define SCHUNK 4000         // edges per scatter chunk (EE/SCHUNK = 400 exact)
#define BUCKW  6250         // NN/8 src-range per XCD bucket

// Read element i of a buffer that is either fp32 (isf32=1) or bf16 (isf32=0).
__device__ __forceinline__ float load_any(const void* p, long i, int isf32) {
    if (isf32) return ((const float*)p)[i];
    unsigned int b = ((unsigned int)(((const unsigned short*)p)[i])) << 16;
    return __uint_as_float(b);
}

__device__ __forceinline__ unsigned short f32_to_bf16_rne(float f) {
    unsigned int b = __float_as_uint(f);
    return (unsigned short)((b + 0x7FFF + ((b >> 16) & 1)) >> 16);
}

__device__ __forceinline__ float bf16_to_f32(unsigned short u) {
    return __uint_as_float(((unsigned int)u) << 16);
}

// ---------------------------------------------------------------------------
// Kernel 0: sampled dtype detection (fp32 misread as bf16 at even indices ->
// huge values with ~45%/sample probability; 256 samples => P(miss) ~1e-67).
// flags[t]=1 means fp32.
// ---------------------------------------------------------------------------
__global__ __launch_bounds__(256) void detect_kernel(
    const void* inp, const void* Mv, const void* W, const void* a, int* flags)
{
    const void* ptrs[4] = { inp, Mv, W, a };
    const long  cnts[4] = { (long)NN * FIN, (long)EE, (long)FIN * FOUT, 2L * FOUT };
    const int t = blockIdx.x;
    const unsigned short* p = (const unsigned short*)ptrs[t];
    const long half = cnts[t] >> 1;
    long step = half / 256; if (step == 0) step = 1;
    const long pos = 2 * (((long)threadIdx.x * step) % half);

    const float v = bf16_to_f32(p[pos]);
    const int bad = (isnan(v) || fabsf(v) > 1e4f) ? 1 : 0;

    __shared__ int sbad[256];
    sbad[threadIdx.x] = bad;
    __syncthreads();
    for (int s = 128; s > 0; s >>= 1) {
        if (threadIdx.x < (unsigned)s) sbad[threadIdx.x] |= sbad[threadIdx.x + s];
        __syncthreads();
    }
    if (threadIdx.x == 0) flags[t] = sbad[0];
}

// ---------------------------------------------------------------------------
// Kernel 1: h = X @ W (fp32 accum, stored bf16), fused s1/s2 projections.
// 16 rows/block, 4 rows/wave. 3125 blocks * 16 = 50000 exactly.
// ---------------------------------------------------------------------------
__global__ __launch_bounds__(256) void gemm_proj_kernel(
    const void* __restrict__ inp,   // [NN, FIN]
    const void* __restrict__ W,     // [FIN, FOUT]
    const void* __restrict__ a,     // [2*FOUT]
    const int* __restrict__ flags,
    unsigned short* __restrict__ h, // [NN, FOUT] bf16
    float* __restrict__ s1,         // [NN]
    float* __restrict__ s2)         // [NN]
{
    __shared__ float Ws[FIN * FOUT];   // 32 KB
    __shared__ float rows[16][FIN];    // 8 KB

    const int tid  = threadIdx.x;
    const int wave = tid >> 6;
    const int lane = tid & 63;
    const int rbase = blockIdx.x * 16;

    const int fI = flags[0], fW = flags[2], fA = flags[3];

    for (int i = tid; i < FIN * FOUT; i += 256)
        Ws[i] = load_any(W, i, fW);

    for (int i = tid; i < 16 * FIN; i += 256) {
        const int r = i >> 7, c = i & 127;
        rows[r][c] = load_any(inp, (long)(rbase + r) * FIN + c, fI);
    }
    __syncthreads();

    const int r0 = wave * 4;
    float a0 = 0.f, a1 = 0.f, a2 = 0.f, a3 = 0.f;
    #pragma unroll 8
    for (int k = 0; k < FIN; ++k) {
        const float w = Ws[k * FOUT + lane];
        a0 = fmaf(rows[r0 + 0][k], w, a0);
        a1 = fmaf(rows[r0 + 1][k], w, a1);
        a2 = fmaf(rows[r0 + 2][k], w, a2);
        a3 = fmaf(rows[r0 + 3][k], w, a3);
    }

    const int row = rbase + r0;
    h[(long)(row + 0) * FOUT + lane] = f32_to_bf16_rne(a0);
    h[(long)(row + 1) * FOUT + lane] = f32_to_bf16_rne(a1);
    h[(long)(row + 2) * FOUT + lane] = f32_to_bf16_rne(a2);
    h[(long)(row + 3) * FOUT + lane] = f32_to_bf16_rne(a3);

    const float av1 = load_any(a, lane, fA);
    const float av2 = load_any(a, lane + 64, fA);
    float accs[4] = { a0, a1, a2, a3 };
    #pragma unroll
    for (int r = 0; r < 4; ++r) {
        float v1 = accs[r] * av1;
        float v2 = accs[r] * av2;
        #pragma unroll
        for (int off = 32; off > 0; off >>= 1) {
            v1 += __shfl_down(v1, off, 64);
            v2 += __shfl_down(v2, off, 64);
        }
        if (lane == 0) { s1[row + r] = v1; s2[row + r] = v2; }
    }
}

// ---------------------------------------------------------------------------
// CSR build: histogram -> scan (3 kernels) -> XCD-partitioned scatter.
// ---------------------------------------------------------------------------
__global__ __launch_bounds__(256) void hist_kernel(
    const int* __restrict__ edge, int* __restrict__ counts)
{
    const int e = blockIdx.x * 256 + threadIdx.x;
    if (e < EE) atomicAdd(&counts[edge[e]], 1);
}

__global__ __launch_bounds__(256) void scan1_kernel(
    const int* __restrict__ counts, int* __restrict__ rowptr, int* __restrict__ bsums)
{
    const int tid = threadIdx.x, wave = tid >> 6, lane = tid & 63;
    const int i = blockIdx.x * 256 + tid;
    const int c = (i < NN) ? counts[i] : 0;
    int x = c;
    #pragma unroll
    for (int off = 1; off < 64; off <<= 1) {
        int y = __shfl_up(x, off, 64);
        if (lane >= off) x += y;
    }
    __shared__ int wsum[4];
    if (lane == 63) wsum[wave] = x;
    __syncthreads();
    int wb = 0;
    for (int w = 0; w < wave; ++w) wb += wsum[w];
    if (i < NN) rowptr[i] = wb + x - c;
    if (tid == 255) bsums[blockIdx.x] = wb + x;
}

__global__ __launch_bounds__(256) void scan2_kernel(
    int* __restrict__ bsums, int* __restrict__ boffs)
{
    const int tid = threadIdx.x, wave = tid >> 6, lane = tid & 63;
    const int c = (tid < NCHUNK) ? bsums[tid] : 0;
    int x = c;
    #pragma unroll
    for (int off = 1; off < 64; off <<= 1) {
        int y = __shfl_up(x, off, 64);
        if (lane >= off) x += y;
    }
    __shared__ int wsum[4];
    if (lane == 63) wsum[wave] = x;
    __syncthreads();
    int wb = 0;
    for (int w = 0; w < wave; ++w) wb += wsum[w];
    if (tid < NCHUNK) boffs[tid] = wb + x - c;
}

__global__ __launch_bounds__(256) void scan3_kernel(
    int* __restrict__ rowptr, const int* __restrict__ boffs, int* __restrict__ cursor)
{
    const int i = blockIdx.x * 256 + threadIdx.x;
    if (i < NN) {
        const int v = rowptr[i] + boffs[blockIdx.x];
        rowptr[i] = v;
        cursor[i] = v;
    }
    if (i == 0) rowptr[NN] = EE;
}

// XCD-partitioned scatter: grid = (EE/SCHUNK) chunks x 8 slots. Block b scans
// chunk b>>3 and emits only edges with src/BUCKW == (b&7). With round-robin
// blockIdx->XCD mapping, each 1/8 of the pairs region is written by exactly
// one XCD -> single-L2 dirty lines, dense coverage -> writeback ~= essential
// bytes (vs 8x amplification when all XCDs scatter everywhere).
// Pair packed to 4B: (dst<<16) | bf16(edge_e)  [dst < 50000 < 2^16; ee > 0].
__global__ __launch_bounds__(256) void scatter_kernel(
    const int* __restrict__ edge,
    const void* __restrict__ Mv,
    const int* __restrict__ flags,
    const float* __restrict__ s1,
    const float* __restrict__ s2,
    int* __restrict__ cursor,
    unsigned int* __restrict__ pairs)
{
    const int xslot = blockIdx.x & 7;
    const int e0 = (blockIdx.x >> 3) * SCHUNK;
    const int fM = flags[1];

    for (int e = e0 + threadIdx.x; e < e0 + SCHUNK; e += 256) {
        const int src = edge[e];
        if (src / BUCKW != xslot) continue;
        const int dst = edge[EE + e];
        const float bias = load_any(Mv, e, fM) * BETA + (1.f - BETA);
        const float x  = s1[src] + bias * s2[dst];
        const float lr = x > 0.f ? x : ALPHA * x;
        const float ee = __expf(lr);
        const int pos = atomicAdd(&cursor[src], 1);
        pairs[pos] = ((unsigned int)dst << 16) | (unsigned int)f32_to_bf16_rne(ee);
    }
}

// ---------------------------------------------------------------------------
// CSR-vector SpMM, fused finalize. One wave per src row; 32 lanes per edge
// (ushort2 = 2 features/lane), 2 edges in flight per wave, unrolled x4.
// ---------------------------------------------------------------------------
__global__ __launch_bounds__(256) void spmm_kernel(
    const int* __restrict__ rowptr,
    const unsigned int* __restrict__ pairs,
    const unsigned short* __restrict__ h,   // bf16 [NN, FOUT]
    const int* __restrict__ flags,
    void* __restrict__ out)
{
    const int wave = threadIdx.x >> 6;
    const int lane = threadIdx.x & 63;
    const int half = lane >> 5;
    const int sl   = lane & 31;
    const int row  = blockIdx.x * 4 + wave;

    const int beg = rowptr[row];
    const int end = rowptr[row + 1];

    float acc0 = 0.f, acc1 = 0.f, rsum = 0.f;
    int j = beg;
    for (; j + 7 < end; j += 8) {
        const unsigned int u0 = pairs[j + 0 + half];
        const unsigned int u1 = pairs[j + 2 + half];
        const unsigned int u2 = pairs[j + 4 + half];
        const unsigned int u3 = pairs[j + 6 + half];
        const ushort2 h0 = *(const ushort2*)&h[(long)(u0 >> 16) * FOUT + 2 * sl];
        const ushort2 h1 = *(const ushort2*)&h[(long)(u1 >> 16) * FOUT + 2 * sl];
        const ushort2 h2 = *(const ushort2*)&h[(long)(u2 >> 16) * FOUT + 2 * sl];
        const ushort2 h3 = *(const ushort2*)&h[(long)(u3 >> 16) * FOUT + 2 * sl];
        const float v0 = bf16_to_f32((unsigned short)u0);
        const float v1 = bf16_to_f32((unsigned short)u1);
        const float v2 = bf16_to_f32((unsigned short)u2);
        const float v3 = bf16_to_f32((unsigned short)u3);
        rsum += (v0 + v1) + (v2 + v3);
        acc0 = fmaf(v0, bf16_to_f32(h0.x), acc0);
        acc1 = fmaf(v0, bf16_to_f32(h0.y), acc1);
        acc0 = fmaf(v1, bf16_to_f32(h1.x), acc0);
        acc1 = fmaf(v1, bf16_to_f32(h1.y), acc1);
        acc0 = fmaf(v2, bf16_to_f32(h2.x), acc0);
        acc1 = fmaf(v2, bf16_to_f32(h2.y), acc1);
        acc0 = fmaf(v3, bf16_to_f32(h3.x), acc0);
        acc1 = fmaf(v3, bf16_to_f32(h3.y), acc1);
    }
    for (; j + 1 < end; j += 2) {
        const unsigned int u = pairs[j + half];
        const ushort2 hv = *(const ushort2*)&h[(long)(u >> 16) * FOUT + 2 * sl];
        const float v = bf16_to_f32((unsigned short)u);
        rsum += v;
        acc0 = fmaf(v, bf16_to_f32(hv.x), acc0);
        acc1 = fmaf(v, bf16_to_f32(hv.y), acc1);
    }
    if (j < end && half == 0) {
        const unsigned int u = pairs[j];
        const ushort2 hv = *(const ushort2*)&h[(long)(u >> 16) * FOUT + 2 * sl];
        const float v = bf16_to_f32((unsigned short)u);
        rsum += v;
        acc0 = fmaf(v, bf16_to_f32(hv.x), acc0);
        acc1 = fmaf(v, bf16_to_f32(hv.y), acc1);
    }

    acc0 += __shfl_xor(acc0, 32, 64);
    acc1 += __shfl_xor(acc1, 32, 64);
    rsum += __shfl_xor(rsum, 32, 64);

    if (half == 0) {
        const float inv = 1.f / rsum;
        float q0 = acc0 * inv;
        float q1 = acc1 * inv;
        q0 = q0 > 0.f ? q0 : (__expf(q0) - 1.f);
        q1 = q1 > 0.f ? q1 : (__expf(q1) - 1.f);
        if (flags[0]) {
            float2* o = (float2*)((float*)out + (long)row * FOUT + 2 * sl);
            *o = make_float2(q0, q1);
        } else {
            ushort2* o = (ushort2*)((unsigned short*)out + (long)row * FOUT + 2 * sl);
            *o = make_ushort2(f32_to_bf16_rne(q0), f32_to_bf16_rne(q1));
        }
    }
}

extern "C" void kernel_launch(void* const* d_in, const int* in_sizes, int n_in,
                              void* d_out, int out_size, void* d_ws, size_t ws_size,
                              hipStream_t stream) {
    const void* inp  = d_in[0];
    const void* Mv   = d_in[1];
    const void* W    = d_in[2];
    const void* a    = d_in[3];
    const int*  edge = (const int*)d_in[4];

    char* p = (char*)d_ws;
    int*            flags  = (int*)p;                          p += 256;
    unsigned short* h      = (unsigned short*)p;               p += ((size_t)NN * FOUT * 2 + 255) / 256 * 256;
    float*          s1     = (float*)p;                        p += ((size_t)NN * 4 + 255) / 256 * 256;
    float*          s2     = (float*)p;                        p += ((size_t)NN * 4 + 255) / 256 * 256;
    int*            rowptr = (int*)p;                          p += ((size_t)(NN + 1) * 4 + 255) / 256 * 256;
    int*            cursor = (int*)p;                          p += ((size_t)NN * 4 + 255) / 256 * 256;
    int*            bsums  = (int*)p;                          p += (NCHUNK * 4 + 255) / 256 * 256;
    int*            boffs  = (int*)p;                          p += (NCHUNK * 4 + 255) / 256 * 256;
    unsigned int*   pairs  = (unsigned int*)p;

    detect_kernel<<<4, 256, 0, stream>>>(inp, Mv, W, a, flags);
    hipMemsetAsync(cursor, 0, (size_t)NN * sizeof(int), stream);   // cursor doubles as counts
    gemm_proj_kernel<<<NN / 16, 256, 0, stream>>>(inp, W, a, flags, h, s1, s2);
    hist_kernel<<<(EE + 255) / 256, 256, 0, stream>>>(edge, cursor);
    scan1_kernel<<<NCHUNK, 256, 0, stream>>>(cursor, rowptr, bsums);
    scan2_kernel<<<1, 256, 0, stream>>>(bsums, boffs);
    scan3_kernel<<<NCHUNK, 256, 0, stream>>>(rowptr, boffs, cursor);
    scatter_kernel<<<(EE / SCHUNK) * 8, 256, 0, stream>>>(edge, Mv, flags, s1, s2, cursor, pairs);
    spmm_kernel<<<NN / 4, 256, 0, stream>>>(rowptr, pairs, h, flags, d_out);
}